// Round 11
// baseline (608.556 us; speedup 1.0000x reference)
//
#include <hip/hip_runtime.h>
#include <hip/hip_bf16.h>
#include <math.h>

#define DDIM 7168
#define NEXP 256
#define NGRP 8
#define TOPKG 4
#define TOPK 8
#define ROUTE_SCALE 2.5f

#define BM 128
#define BN 128
#define BK 64
#define KSPLIT 4
#define KPER (DDIM / KSPLIT)     // 1792
#define NSTEP (KPER / BK)        // 28
#define NKT (DDIM / BK)          // 112 global k-tiles
#define BT_ELEMS (BN * BK * 2)   // 16384 shorts = 32 KB per (kt, nh) tile

typedef __attribute__((ext_vector_type(8))) short bf16x8;
typedef __attribute__((ext_vector_type(4))) float f32x4;
typedef unsigned int u32;
typedef unsigned short ushort_t;

static __device__ __forceinline__ ushort_t bf16_rne(float f) {
    u32 b = __float_as_uint(f);
    u32 r = (b + 0x7fffu + ((b >> 16) & 1u)) >> 16;
    return (ushort_t)r;
}
static __device__ __forceinline__ float bf16_to_f32(ushort_t h) {
    return __uint_as_float(((u32)h) << 16);
}

// keep a 16B vector live without cost (anti-DCE, rule #17)
#define SINKV(v) do {                                             \
        const int* p_ = (const int*)&(v);                         \
        asm volatile("" :: "v"(p_[0]), "v"(p_[1]), "v"(p_[2]), "v"(p_[3])); \
    } while (0)

// ---------------------------------------------------------------------------
// Kernel 0: split w into hi/lo bf16, fragment-linear tiles per (kt, nh).
// Tile (32 KB): [split(2)][ks(2)][fn(8)][lane(64)][8 bf16]  (unchanged)
// ---------------------------------------------------------------------------
__global__ __launch_bounds__(256) void wsplit_kernel(const float* __restrict__ w,
                                                     short* __restrict__ wsp)
{
    const int kt = blockIdx.x;      // 0..111
    const int e  = threadIdx.x;     // expert 0..255
    const float* wp = w + (size_t)e * DDIM + (size_t)kt * BK;
    const int nh = e >> 7, fn = (e >> 4) & 7, er = e & 15;
    short* tb = wsp + ((size_t)kt * 2 + nh) * BT_ELEMS;
    #pragma unroll
    for (int ks = 0; ks < 2; ks++) {
        #pragma unroll
        for (int jg = 0; jg < 4; jg++) {
            float f[8];
            *(float4*)&f[0] = *(const float4*)(wp + ks * 32 + jg * 8);
            *(float4*)&f[4] = *(const float4*)(wp + ks * 32 + jg * 8 + 4);
            ushort_t h[8], l[8];
            #pragma unroll
            for (int j = 0; j < 8; j++) {
                h[j] = bf16_rne(f[j]);
                l[j] = bf16_rne(f[j] - bf16_to_f32(h[j]));
            }
            const int lane = jg * 16 + er;
            *(uint4*)(tb + ((size_t)((0 * 2 + ks) * 8 + fn) * 64 + lane) * 8) = *(uint4*)h;
            *(uint4*)(tb + ((size_t)((1 * 2 + ks) * 8 + fn) * 64 + lane) * 8) = *(uint4*)l;
        }
    }
}

// ---------------------------------------------------------------------------
// Kernel 1 (ABLATION TEMPLATE): split-precision bf16 MFMA GEMM, R10 structure.
// V=0: R10-exact MFMA order (3 chained MFMAs on same acc, distance 1).
// V=1: pass-major MFMA order (same-acc distance 8) — dep-chain probe.
// V=3: V1 with ONLY the Ah*Bh pass (16 vs 48 MFMA); al/blv sunk live — MFMA-count probe.
// V=4: V1 with lo-convert chain removed (al := ah; same MFMA/ds count) — convert-VALU probe.
// All variants: identical grid/LDS/staging/sync (uniform vmcnt(8) ledger).
// ---------------------------------------------------------------------------
template<int V>
__global__ __launch_bounds__(512, 4) void gemm_tpl(
    const float* __restrict__ x, const short* __restrict__ wsp,
    float* __restrict__ part, int Btok)
{
    __shared__ short Blds[2][BT_ELEMS];   // 2 x 32 KB

    const int bid  = blockIdx.x;
    const int xcd  = bid & 7;
    const int ksp  = xcd & 3;
    const int nh   = xcd >> 2;
    const int mt   = bid >> 3;            // 0..63
    const int m0   = mt * BM;
    const int kbase = ksp * KPER;
    const int t    = threadIdx.x;
    const int wid  = t >> 6, lane = t & 63;
    const int wm   = wid >> 1, wn = wid & 1;
    const int lr   = lane & 15, lg = lane >> 4;

    const short* wt0 = wsp + ((size_t)(ksp * NSTEP) * 2 + nh) * BT_ELEMS;
    const float* abase = x + (size_t)(m0 + wm * 32 + lr) * DDIM + kbase + lg * 8;

#define STAGE_B(stp, dst) do {                                                             \
        const short* gt_ = wt0 + (size_t)(stp) * 2 * BT_ELEMS;                             \
        _Pragma("unroll")                                                                  \
        for (int i_ = 0; i_ < 4; i_++) {                                                   \
            const int off_ = wid * 4096 + i_ * 1024;                                       \
            __builtin_amdgcn_global_load_lds(                                              \
                (const __attribute__((address_space(1))) u32*)((const char*)gt_ + off_ + lane * 16), \
                (__attribute__((address_space(3))) u32*)((char*)(dst) + off_),             \
                16, 0, 0);                                                                 \
        } } while (0)

#define LOAD_A(stp) do {                                                                   \
        _Pragma("unroll")                                                                  \
        for (int fm_ = 0; fm_ < 2; fm_++)                                                  \
            _Pragma("unroll")                                                              \
            for (int ks_ = 0; ks_ < 2; ks_++) {                                            \
                const float* ap_ = abase + (size_t)fm_ * 16 * DDIM + (size_t)(stp) * BK + ks_ * 32; \
                *(float4*)&a_cur[fm_][ks_][0] = *(const float4*)(ap_);                     \
                *(float4*)&a_cur[fm_][ks_][4] = *(const float4*)(ap_ + 4);                 \
            } } while (0)

    f32x4 acc[2][4];
    #pragma unroll
    for (int i = 0; i < 2; i++)
        #pragma unroll
        for (int j = 0; j < 4; j++) acc[i][j] = (f32x4){0.f, 0.f, 0.f, 0.f};

    float a_cur[2][2][8];

    STAGE_B(0, &Blds[0][0]);
    LOAD_A(0);

    for (int st = 0; st < NSTEP; st++) {
        const int cur = st & 1;
        asm volatile("s_waitcnt vmcnt(8)" ::: "memory");
        asm volatile("s_waitcnt lgkmcnt(0)" ::: "memory");
        __builtin_amdgcn_s_barrier();

        if (st + 1 < NSTEP) STAGE_B(st + 1, &Blds[cur ^ 1][0]);

        // ---- convert A(st) -> hi/lo fragments ----
        bf16x8 ah[2][2], al[2][2];
        #pragma unroll
        for (int fm = 0; fm < 2; fm++)
            #pragma unroll
            for (int ks = 0; ks < 2; ks++) {
                union { bf16x8 v; short s[8]; } H, L;
                #pragma unroll
                for (int j = 0; j < 8; j++) {
                    union { __hip_bfloat16 b; short s; } cv;
                    cv.b = __float2bfloat16(a_cur[fm][ks][j]);
                    H.s[j] = cv.s;
                    if constexpr (V == 4) {
                        L.s[j] = cv.s;   // lo-chain removed (probe)
                    } else {
                        float hf = __uint_as_float(((u32)(ushort_t)cv.s) << 16);
                        cv.b = __float2bfloat16(a_cur[fm][ks][j] - hf);
                        L.s[j] = cv.s;
                    }
                }
                ah[fm][ks] = H.v;
                al[fm][ks] = L.v;
            }

        if (st + 1 < NSTEP) LOAD_A(st + 1);

        // ---- MFMA section (the ablation variable) ----
        if constexpr (V == 0) {
            // R10-exact: 3 chained MFMAs per acc, distance 1
            #pragma unroll
            for (int fn = 0; fn < 4; fn++) {
                #pragma unroll
                for (int ks = 0; ks < 2; ks++) {
                    const bf16x8 bh = *(const bf16x8*)&Blds[cur][((size_t)((0 * 2 + ks) * 8 + wn * 4 + fn) * 64 + lane) * 8];
                    const bf16x8 bl = *(const bf16x8*)&Blds[cur][((size_t)((1 * 2 + ks) * 8 + wn * 4 + fn) * 64 + lane) * 8];
                    #pragma unroll
                    for (int fm = 0; fm < 2; fm++) {
                        acc[fm][fn] = __builtin_amdgcn_mfma_f32_16x16x32_bf16(ah[fm][ks], bh, acc[fm][fn], 0, 0, 0);
                        acc[fm][fn] = __builtin_amdgcn_mfma_f32_16x16x32_bf16(ah[fm][ks], bl, acc[fm][fn], 0, 0, 0);
                        acc[fm][fn] = __builtin_amdgcn_mfma_f32_16x16x32_bf16(al[fm][ks], bh, acc[fm][fn], 0, 0, 0);
                    }
                }
            }
        } else {
            // pass-major: same-acc dependency distance = 8 MFMAs
            #pragma unroll
            for (int ks = 0; ks < 2; ks++) {
                bf16x8 bhv[4], blv[4];
                #pragma unroll
                for (int fn = 0; fn < 4; fn++) {
                    bhv[fn] = *(const bf16x8*)&Blds[cur][((size_t)((0 * 2 + ks) * 8 + wn * 4 + fn) * 64 + lane) * 8];
                    blv[fn] = *(const bf16x8*)&Blds[cur][((size_t)((1 * 2 + ks) * 8 + wn * 4 + fn) * 64 + lane) * 8];
                }
                // pass HH
                #pragma unroll
                for (int fn = 0; fn < 4; fn++)
                    #pragma unroll
                    for (int fm = 0; fm < 2; fm++)
                        acc[fm][fn] = __builtin_amdgcn_mfma_f32_16x16x32_bf16(ah[fm][ks], bhv[fn], acc[fm][fn], 0, 0, 0);
                if constexpr (V == 3) {
                    // MFMA-count probe: keep bl ds_reads + al converts live, no more MFMAs
                    #pragma unroll
                    for (int fn = 0; fn < 4; fn++) SINKV(blv[fn]);
                } else {
                    // pass HL
                    #pragma unroll
                    for (int fn = 0; fn < 4; fn++)
                        #pragma unroll
                        for (int fm = 0; fm < 2; fm++)
                            acc[fm][fn] = __builtin_amdgcn_mfma_f32_16x16x32_bf16(ah[fm][ks], blv[fn], acc[fm][fn], 0, 0, 0);
                    // pass LH
                    #pragma unroll
                    for (int fn = 0; fn < 4; fn++)
                        #pragma unroll
                        for (int fm = 0; fm < 2; fm++)
                            acc[fm][fn] = __builtin_amdgcn_mfma_f32_16x16x32_bf16(al[fm][ks], bhv[fn], acc[fm][fn], 0, 0, 0);
                }
            }
            if constexpr (V == 3) {
                #pragma unroll
                for (int fm = 0; fm < 2; fm++)
                    #pragma unroll
                    for (int ks = 0; ks < 2; ks++) SINKV(al[fm][ks]);
            }
        }
    }
#undef STAGE_B
#undef LOAD_A

    float* pp = part + (size_t)ksp * (size_t)Btok * NEXP;
    #pragma unroll
    for (int fm = 0; fm < 2; fm++) {
        const int row0 = m0 + wm * 32 + fm * 16 + lg * 4;
        #pragma unroll
        for (int fn = 0; fn < 4; fn++) {
            const int col = nh * 128 + wn * 64 + fn * 16 + lr;
            #pragma unroll
            for (int rr = 0; rr < 4; rr++)
                pp[(size_t)(row0 + rr) * NEXP + col] = acc[fm][fn][rr];
        }
    }
}

// ---------------------------------------------------------------------------
// Kernel 2: reduce split-K partials + sigmoid + full gating. (unchanged)
// ---------------------------------------------------------------------------
__global__ __launch_bounds__(256) void gate_kernel(
    const float* __restrict__ part, const float* __restrict__ bias,
    float* __restrict__ out_w, float* __restrict__ out_i, int B)
{
    const int lane = threadIdx.x & 63;
    const int wid  = threadIdx.x >> 6;
    const int row  = blockIdx.x * 4 + wid;
    if (row >= B) return;

    const size_t plane = (size_t)B * NEXP;
    const float* pr = part + (size_t)row * NEXP + lane * 4;
    float4 v0 = *(const float4*)(pr);
    float4 v1 = *(const float4*)(pr + plane);
    float4 v2 = *(const float4*)(pr + 2 * plane);
    float4 v3 = *(const float4*)(pr + 3 * plane);
    float sc[4] = { v0.x + v1.x + v2.x + v3.x,
                    v0.y + v1.y + v2.y + v3.y,
                    v0.z + v1.z + v2.z + v3.z,
                    v0.w + v1.w + v2.w + v3.w };
    float4 bv = *(const float4*)(bias + lane * 4);
    const float bb[4] = { bv.x, bv.y, bv.z, bv.w };

    float so[4], sb[4];
    #pragma unroll
    for (int j = 0; j < 4; j++) {
        so[j] = 1.0f / (1.0f + expf(-sc[j]));
        sb[j] = so[j] + bb[j];
    }

    float m1 = sb[0], m2 = -INFINITY;
    #pragma unroll
    for (int j = 1; j < 4; j++) {
        if (sb[j] > m1)      { m2 = m1; m1 = sb[j]; }
        else if (sb[j] > m2) { m2 = sb[j]; }
    }
    #pragma unroll
    for (int m = 1; m <= 4; m <<= 1) {
        float o1 = __shfl_xor(m1, m);
        float o2 = __shfl_xor(m2, m);
        float hi = fmaxf(m1, o1);
        float lo = fminf(m1, o1);
        m1 = hi;
        m2 = fmaxf(lo, fmaxf(m2, o2));
    }
    float gscore = m1 + m2;
    int g = lane >> 3;

    float gs[NGRP];
    #pragma unroll
    for (int gg = 0; gg < NGRP; gg++) gs[gg] = __shfl(gscore, gg * 8);
    int rank = 0;
    #pragma unroll
    for (int gg = 0; gg < NGRP; gg++) {
        if (gg == g) continue;
        if (gs[gg] > gs[g] || (gs[gg] == gs[g] && gg < g)) rank++;
    }
    const bool selg = (rank < TOPKG);
    float mv[4];
    #pragma unroll
    for (int j = 0; j < 4; j++) mv[j] = selg ? sb[j] : -INFINITY;

    float wsel[TOPK];
    int   isel[TOPK];
    float wsum = 0.f;
    #pragma unroll
    for (int it = 0; it < TOPK; it++) {
        float v = mv[0]; int jj = 0;
        #pragma unroll
        for (int j = 1; j < 4; j++)
            if (mv[j] > v) { v = mv[j]; jj = j; }
        int gi = (lane << 2) | jj;
        #pragma unroll
        for (int m = 1; m < 64; m <<= 1) {
            float ov = __shfl_xor(v, m);
            int   oi = __shfl_xor(gi, m);
            if (ov > v || (ov == v && oi < gi)) { v = ov; gi = oi; }
        }
        int slot = gi & 3, src = gi >> 2;
        float cand = (slot == 0) ? so[0] : (slot == 1) ? so[1] : (slot == 2) ? so[2] : so[3];
        float sval = __shfl(cand, src);
        wsel[it] = sval; isel[it] = gi; wsum += sval;
        if (lane == src) mv[slot] = -INFINITY;
    }

    if (lane == 0) {
        float scl = ROUTE_SCALE / wsum;
        #pragma unroll
        for (int it = 0; it < TOPK; it++) {
            out_w[(size_t)row * TOPK + it] = wsel[it] * scl;
            out_i[(size_t)row * TOPK + it] = (float)isel[it];
        }
    }
}

extern "C" void kernel_launch(void* const* d_in, const int* in_sizes, int n_in,
                              void* d_out, int out_size, void* d_ws, size_t ws_size,
                              hipStream_t stream)
{
    const float* x    = (const float*)d_in[0];
    const float* w    = (const float*)d_in[1];
    const float* bias = (const float*)d_in[2];
    const int B = in_sizes[0] / DDIM;           // 8192

    float* part = (float*)d_ws;
    short* wsp  = (short*)((char*)d_ws + (size_t)KSPLIT * B * NEXP * sizeof(float));

    float* out_w = (float*)d_out;
    float* out_i = out_w + (size_t)B * TOPK;

    const int grid = (B / BM) * 2 * KSPLIT;     // 512

    hipLaunchKernelGGL(wsplit_kernel, dim3(NKT), dim3(256), 0, stream, w, wsp);
    // ---- ablation: per-dispatch dur_us in rocprof is the A/B table ----
    hipLaunchKernelGGL((gemm_tpl<1>), dim3(grid), dim3(512), 0, stream, x, wsp, part, B);  // dep-chain probe
    hipLaunchKernelGGL((gemm_tpl<3>), dim3(grid), dim3(512), 0, stream, x, wsp, part, B);  // MFMA-count probe
    hipLaunchKernelGGL((gemm_tpl<4>), dim3(grid), dim3(512), 0, stream, x, wsp, part, B);  // convert-VALU probe
    hipLaunchKernelGGL((gemm_tpl<0>), dim3(grid), dim3(512), 0, stream, x, wsp, part, B);  // R10 baseline, FINAL (correct output)
    hipLaunchKernelGGL(gate_kernel, dim3((B + 3) / 4), dim3(256), 0, stream,
                       part, bias, out_w, out_i, B);
}

// Round 12
// 206.036 us; speedup vs baseline: 2.9536x; 2.9536x over previous
//
#include <hip/hip_runtime.h>
#include <hip/hip_bf16.h>
#include <math.h>

#define DDIM 7168
#define NEXP 256
#define NGRP 8
#define TOPKG 4
#define TOPK 8
#define ROUTE_SCALE 2.5f

#define BM 32
#define BN 256
#define BK 64
#define KSPLIT 4
#define KPER (DDIM / KSPLIT)       // 1792
#define NSTEP (KPER / BK)          // 28
#define NKT (DDIM / BK)            // 112 k-tiles
#define BT_ELEMS (NEXP * BK * 2)   // 32768 shorts = 64 KB per kt tile

typedef __attribute__((ext_vector_type(8))) short bf16x8;
typedef __attribute__((ext_vector_type(4))) float f32x4;
typedef unsigned int u32;
typedef unsigned short ushort_t;

static __device__ __forceinline__ ushort_t bf16_rne(float f) {
    u32 b = __float_as_uint(f);
    u32 r = (b + 0x7fffu + ((b >> 16) & 1u)) >> 16;
    return (ushort_t)r;
}
static __device__ __forceinline__ float bf16_to_f32(ushort_t h) {
    return __uint_as_float(((u32)h) << 16);
}

// ---------------------------------------------------------------------------
// Kernel 0: split w into hi/lo bf16, fragment-linear per BK=64 k-tile.
// Tile (64 KB): [pass(2)][ks(2)][fnb(16)][lane(64)][8 bf16]
// element = split of W[fnb*16 + (lane&15)][kt*64 + ks*32 + (lane>>4)*8 + j]
// => GEMM B-fragment reads are consecutive 16B per lane (perfect coalescing,
//    read DIRECTLY from L2 — no LDS staging in this design).
// ---------------------------------------------------------------------------
__global__ __launch_bounds__(256) void wsplit_kernel(const float* __restrict__ w,
                                                     short* __restrict__ wsp)
{
    const int kt = blockIdx.x;      // 0..111
    const int e  = threadIdx.x;     // expert 0..255
    const float* wp = w + (size_t)e * DDIM + (size_t)kt * BK;
    const int fnb = e >> 4, er = e & 15;
    short* tb = wsp + (size_t)kt * BT_ELEMS;
    #pragma unroll
    for (int ks = 0; ks < 2; ks++) {
        #pragma unroll
        for (int jg = 0; jg < 4; jg++) {
            float f[8];
            *(float4*)&f[0] = *(const float4*)(wp + ks * 32 + jg * 8);
            *(float4*)&f[4] = *(const float4*)(wp + ks * 32 + jg * 8 + 4);
            ushort_t h[8], l[8];
            #pragma unroll
            for (int j = 0; j < 8; j++) {
                h[j] = bf16_rne(f[j]);
                l[j] = bf16_rne(f[j] - bf16_to_f32(h[j]));
            }
            const int lane = jg * 16 + er;
            *(uint4*)(tb + ((size_t)((0 * 2 + ks) * 16 + fnb) * 64 + lane) * 8) = *(uint4*)h;
            *(uint4*)(tb + ((size_t)((1 * 2 + ks) * 16 + fnb) * 64 + lane) * 8) = *(uint4*)l;
        }
    }
}

// ---------------------------------------------------------------------------
// Kernel 1: split-precision bf16 MFMA GEMM — BARRIER-FREE, LDS-FREE.
// R11 ablation verdict: step-body compute is irrelevant (16 vs 48 MFMA =
// same time); the lockstep wait+barrier skeleton is the binder. This design
// removes it: w (7.3 MB packed; 1.84 MB per K-quarter) is L2-resident per
// XCD, so each wave loads B fragments directly from L2 as coalesced
// dwordx4 — no __syncthreads, no global_load_lds, no LDS. 8 independent
// waves/CU of TLP + compiler's own waitcnt scheduling hide all latency.
// grid = 256 mt x 4 ksp = 1024 blocks (2/CU); 256 thr = 4 waves spanning N
// (wave-tile 32x64, wn = wid); BK=64 -> 48 MFMA/wave/step.
// A: 1-step-ahead register ping-pong (named aA/aB, 2x-unrolled loop).
// XCD-bijective: xcd = bid&7 -> ksp = xcd&3 (each XCD's w slice L2-hot).
// ---------------------------------------------------------------------------
__global__ __launch_bounds__(256, 2) void gemm_split_kernel(
    const float* __restrict__ x, const short* __restrict__ wsp,
    float* __restrict__ part, int Btok)
{
    const int bid  = blockIdx.x;
    const int xcd  = bid & 7;
    const int ksp  = xcd & 3;
    const int mt   = (bid >> 3) * 2 + (xcd >> 2);   // 0..255, bijective
    const int m0   = mt * BM;
    const int kbase = ksp * KPER;
    const int t    = threadIdx.x;
    const int wn   = t >> 6, lane = t & 63;         // wave wn owns experts wn*64..wn*64+63
    const int lr   = lane & 15, lg = lane >> 4;

    const short* wt0 = wsp + (size_t)(ksp * NSTEP) * BT_ELEMS;
    // A: rows m0 + fm*16 + lr ; k = kbase + st*64 + ks*32 + lg*8 (all waves same rows; L1 dedups)
    const float* abase = x + (size_t)(m0 + lr) * DDIM + kbase + lg * 8;

#define LOAD_A(stp, ABUF) do {                                                             \
        _Pragma("unroll")                                                                  \
        for (int fm_ = 0; fm_ < 2; fm_++)                                                  \
            _Pragma("unroll")                                                              \
            for (int ks_ = 0; ks_ < 2; ks_++) {                                            \
                const float* ap_ = abase + (size_t)fm_ * 16 * DDIM + (size_t)(stp) * BK + ks_ * 32; \
                *(float4*)&ABUF[fm_][ks_][0] = *(const float4*)(ap_);                      \
                *(float4*)&ABUF[fm_][ks_][4] = *(const float4*)(ap_ + 4);                  \
            } } while (0)

    f32x4 acc[2][4];
    #pragma unroll
    for (int i = 0; i < 2; i++)
        #pragma unroll
        for (int j = 0; j < 4; j++) acc[i][j] = (f32x4){0.f, 0.f, 0.f, 0.f};

    float aA[2][2][8], aB[2][2][8];

    LOAD_A(0, aA);

#define STEP_BODY(st, ACUR, ANXT) do {                                                     \
        /* issue A(st+1) prefetch first (lands during this step) */                        \
        if ((st) + 1 < NSTEP) LOAD_A((st) + 1, ANXT);                                      \
        /* issue all 16 B-fragment loads for this step (L2-hit, coalesced) */              \
        const short* bt_ = wt0 + (size_t)(st) * BT_ELEMS;                                  \
        bf16x8 bhv[2][4], blv[2][4];                                                       \
        _Pragma("unroll")                                                                  \
        for (int ks = 0; ks < 2; ks++)                                                     \
            _Pragma("unroll")                                                              \
            for (int fn = 0; fn < 4; fn++) {                                               \
                bhv[ks][fn] = *(const bf16x8*)&bt_[((size_t)((0 * 2 + ks) * 16 + wn * 4 + fn) * 64 + lane) * 8]; \
                blv[ks][fn] = *(const bf16x8*)&bt_[((size_t)((1 * 2 + ks) * 16 + wn * 4 + fn) * 64 + lane) * 8]; \
            }                                                                              \
        /* convert A(st) -> hi/lo fragments (A landed a full step ago) */                  \
        bf16x8 ah[2][2], al[2][2];                                                         \
        _Pragma("unroll")                                                                  \
        for (int fm = 0; fm < 2; fm++)                                                     \
            _Pragma("unroll")                                                              \
            for (int ks = 0; ks < 2; ks++) {                                               \
                union { bf16x8 v; short s[8]; } H_, L_;                                    \
                _Pragma("unroll")                                                          \
                for (int j = 0; j < 8; j++) {                                              \
                    union { __hip_bfloat16 b; short s; } cv_;                              \
                    cv_.b = __float2bfloat16(ACUR[fm][ks][j]);                             \
                    H_.s[j] = cv_.s;                                                       \
                    float hf_ = __uint_as_float(((u32)(ushort_t)cv_.s) << 16);             \
                    cv_.b = __float2bfloat16(ACUR[fm][ks][j] - hf_);                       \
                    L_.s[j] = cv_.s;                                                       \
                }                                                                          \
                ah[fm][ks] = H_.v;                                                         \
                al[fm][ks] = L_.v;                                                         \
            }                                                                              \
        /* MFMA, pass-major (same-acc dep distance 8) */                                   \
        _Pragma("unroll")                                                                  \
        for (int ks = 0; ks < 2; ks++) {                                                   \
            _Pragma("unroll")                                                              \
            for (int fn = 0; fn < 4; fn++)                                                 \
                _Pragma("unroll")                                                          \
                for (int fm = 0; fm < 2; fm++)                                             \
                    acc[fm][fn] = __builtin_amdgcn_mfma_f32_16x16x32_bf16(ah[fm][ks], bhv[ks][fn], acc[fm][fn], 0, 0, 0); \
            _Pragma("unroll")                                                              \
            for (int fn = 0; fn < 4; fn++)                                                 \
                _Pragma("unroll")                                                          \
                for (int fm = 0; fm < 2; fm++)                                             \
                    acc[fm][fn] = __builtin_amdgcn_mfma_f32_16x16x32_bf16(ah[fm][ks], blv[ks][fn], acc[fm][fn], 0, 0, 0); \
            _Pragma("unroll")                                                              \
            for (int fn = 0; fn < 4; fn++)                                                 \
                _Pragma("unroll")                                                          \
                for (int fm = 0; fm < 2; fm++)                                             \
                    acc[fm][fn] = __builtin_amdgcn_mfma_f32_16x16x32_bf16(al[fm][ks], bhv[ks][fn], acc[fm][fn], 0, 0, 0); \
        }                                                                                  \
    } while (0)

    for (int st2 = 0; st2 < NSTEP; st2 += 2) {
        STEP_BODY(st2,     aA, aB);
        STEP_BODY(st2 + 1, aB, aA);
    }
#undef STEP_BODY
#undef LOAD_A

    // ---- epilogue: fp32 partials (C/D map: col=lane&15, row=(lane>>4)*4+reg) ----
    float* pp = part + (size_t)ksp * (size_t)Btok * NEXP;
    #pragma unroll
    for (int fm = 0; fm < 2; fm++) {
        const int row0 = m0 + fm * 16 + lg * 4;
        #pragma unroll
        for (int fn = 0; fn < 4; fn++) {
            const int col = wn * 64 + fn * 16 + lr;
            #pragma unroll
            for (int rr = 0; rr < 4; rr++)
                pp[(size_t)(row0 + rr) * NEXP + col] = acc[fm][fn][rr];
        }
    }
}

// ---------------------------------------------------------------------------
// Kernel 2: reduce split-K partials + sigmoid + full gating, one wave per row.
// (unchanged — proven)
// ---------------------------------------------------------------------------
__global__ __launch_bounds__(256) void gate_kernel(
    const float* __restrict__ part, const float* __restrict__ bias,
    float* __restrict__ out_w, float* __restrict__ out_i, int B)
{
    const int lane = threadIdx.x & 63;
    const int wid  = threadIdx.x >> 6;
    const int row  = blockIdx.x * 4 + wid;
    if (row >= B) return;

    const size_t plane = (size_t)B * NEXP;
    const float* pr = part + (size_t)row * NEXP + lane * 4;
    float4 v0 = *(const float4*)(pr);
    float4 v1 = *(const float4*)(pr + plane);
    float4 v2 = *(const float4*)(pr + 2 * plane);
    float4 v3 = *(const float4*)(pr + 3 * plane);
    float sc[4] = { v0.x + v1.x + v2.x + v3.x,
                    v0.y + v1.y + v2.y + v3.y,
                    v0.z + v1.z + v2.z + v3.z,
                    v0.w + v1.w + v2.w + v3.w };
    float4 bv = *(const float4*)(bias + lane * 4);
    const float bb[4] = { bv.x, bv.y, bv.z, bv.w };

    float so[4], sb[4];
    #pragma unroll
    for (int j = 0; j < 4; j++) {
        so[j] = 1.0f / (1.0f + expf(-sc[j]));
        sb[j] = so[j] + bb[j];
    }

    float m1 = sb[0], m2 = -INFINITY;
    #pragma unroll
    for (int j = 1; j < 4; j++) {
        if (sb[j] > m1)      { m2 = m1; m1 = sb[j]; }
        else if (sb[j] > m2) { m2 = sb[j]; }
    }
    #pragma unroll
    for (int m = 1; m <= 4; m <<= 1) {
        float o1 = __shfl_xor(m1, m);
        float o2 = __shfl_xor(m2, m);
        float hi = fmaxf(m1, o1);
        float lo = fminf(m1, o1);
        m1 = hi;
        m2 = fmaxf(lo, fmaxf(m2, o2));
    }
    float gscore = m1 + m2;
    int g = lane >> 3;

    float gs[NGRP];
    #pragma unroll
    for (int gg = 0; gg < NGRP; gg++) gs[gg] = __shfl(gscore, gg * 8);
    int rank = 0;
    #pragma unroll
    for (int gg = 0; gg < NGRP; gg++) {
        if (gg == g) continue;
        if (gs[gg] > gs[g] || (gs[gg] == gs[g] && gg < g)) rank++;
    }
    const bool selg = (rank < TOPKG);
    float mv[4];
    #pragma unroll
    for (int j = 0; j < 4; j++) mv[j] = selg ? sb[j] : -INFINITY;

    float wsel[TOPK];
    int   isel[TOPK];
    float wsum = 0.f;
    #pragma unroll
    for (int it = 0; it < TOPK; it++) {
        float v = mv[0]; int jj = 0;
        #pragma unroll
        for (int j = 1; j < 4; j++)
            if (mv[j] > v) { v = mv[j]; jj = j; }
        int gi = (lane << 2) | jj;
        #pragma unroll
        for (int m = 1; m < 64; m <<= 1) {
            float ov = __shfl_xor(v, m);
            int   oi = __shfl_xor(gi, m);
            if (ov > v || (ov == v && oi < gi)) { v = ov; gi = oi; }
        }
        int slot = gi & 3, src = gi >> 2;
        float cand = (slot == 0) ? so[0] : (slot == 1) ? so[1] : (slot == 2) ? so[2] : so[3];
        float sval = __shfl(cand, src);
        wsel[it] = sval; isel[it] = gi; wsum += sval;
        if (lane == src) mv[slot] = -INFINITY;
    }

    if (lane == 0) {
        float scl = ROUTE_SCALE / wsum;
        #pragma unroll
        for (int it = 0; it < TOPK; it++) {
            out_w[(size_t)row * TOPK + it] = wsel[it] * scl;
            out_i[(size_t)row * TOPK + it] = (float)isel[it];
        }
    }
}

extern "C" void kernel_launch(void* const* d_in, const int* in_sizes, int n_in,
                              void* d_out, int out_size, void* d_ws, size_t ws_size,
                              hipStream_t stream)
{
    const float* x    = (const float*)d_in[0];
    const float* w    = (const float*)d_in[1];
    const float* bias = (const float*)d_in[2];
    const int B = in_sizes[0] / DDIM;           // 8192

    // ws layout: [ part: 4 * B * 256 f32 = 32 MB ][ wsp: 112 tiles * 64 KB = 7.34 MB ]
    float* part = (float*)d_ws;
    short* wsp  = (short*)((char*)d_ws + (size_t)KSPLIT * B * NEXP * sizeof(float));

    float* out_w = (float*)d_out;
    float* out_i = out_w + (size_t)B * TOPK;

    hipLaunchKernelGGL(wsplit_kernel, dim3(NKT), dim3(256), 0, stream, w, wsp);
    hipLaunchKernelGGL(gemm_split_kernel, dim3((B / BM) * KSPLIT), dim3(256), 0, stream,
                       x, wsp, part, B);
    hipLaunchKernelGGL(gate_kernel, dim3((B + 3) / 4), dim3(256), 0, stream,
                       part, bias, out_w, out_i, B);
}

// Round 13
// 126.263 us; speedup vs baseline: 4.8197x; 1.6318x over previous
//
#include <hip/hip_runtime.h>
#include <hip/hip_bf16.h>
#include <math.h>

#define DDIM 7168
#define NEXP 256
#define NGRP 8
#define TOPKG 4
#define TOPK 8
#define ROUTE_SCALE 2.5f

#define BM 64
#define BN 256
#define BK 32
#define KSPLIT 4
#define KPER (DDIM / KSPLIT)        // 1792
#define NSTEP (KPER / BK)           // 56
#define NKTILE (DDIM / BK)          // 224
#define BT_ELEMS (NEXP * BK * 2)    // 16384 shorts = 32 KB per k-tile

typedef __attribute__((ext_vector_type(8))) short bf16x8;
typedef __attribute__((ext_vector_type(4))) float f32x4;
typedef unsigned int u32;
typedef unsigned short ushort_t;

static __device__ __forceinline__ ushort_t bf16_rne(float f) {
    u32 b = __float_as_uint(f);
    u32 r = (b + 0x7fffu + ((b >> 16) & 1u)) >> 16;
    return (ushort_t)r;
}
static __device__ __forceinline__ float bf16_to_f32(ushort_t h) {
    return __uint_as_float(((u32)h) << 16);
}
// hi = bf16(f) via HW cvt; lo = bf16(f - hi)
static __device__ __forceinline__ void split_elem(float f, short& h, short& l) {
    union { __hip_bfloat16 b; short s; } cv;
    cv.b = __float2bfloat16(f);
    h = cv.s;
    float hf = __uint_as_float(((u32)(ushort_t)cv.s) << 16);
    cv.b = __float2bfloat16(f - hf);
    l = cv.s;
}

// ---------------------------------------------------------------------------
// Kernel 0: split w into hi/lo bf16, fragment-linear per BK=32 k-tile.
// Tile (32 KB): [pass(2)][fn(16)][lane(64)][8 bf16]  — R3-proven layout.
// ---------------------------------------------------------------------------
__global__ __launch_bounds__(256) void wsplit_kernel(const float* __restrict__ w,
                                                     short* __restrict__ wsp)
{
    const int kt = blockIdx.x;      // 0..223
    const int e  = threadIdx.x;     // expert 0..255
    const float* wp = w + (size_t)e * DDIM + (size_t)kt * BK;
    short* tb = wsp + (size_t)kt * BT_ELEMS;
    const int fn = e >> 4, er = e & 15;
    #pragma unroll
    for (int jg = 0; jg < 4; jg++) {
        float f[8];
        *(float4*)&f[0] = *(const float4*)(wp + jg * 8);
        *(float4*)&f[4] = *(const float4*)(wp + jg * 8 + 4);
        ushort_t h[8], l[8];
        #pragma unroll
        for (int j = 0; j < 8; j++) {
            h[j] = bf16_rne(f[j]);
            l[j] = bf16_rne(f[j] - bf16_to_f32(h[j]));
        }
        const int lane = jg * 16 + er;
        *(uint4*)(tb + ((size_t)(0 * 16 + fn) * 64 + lane) * 8) = *(uint4*)h;
        *(uint4*)(tb + ((size_t)(1 * 16 + fn) * 64 + lane) * 8) = *(uint4*)l;
    }
}

// ---------------------------------------------------------------------------
// Kernel 1: split-precision bf16 MFMA GEMM — COALESCED-A design.
// R11/R12 ablations: MFMA count, convert VALU, dep-chains, barriers, occupancy
// all irrelevant. Surviving theory: TA transaction serialization from the
// DDIM-strided A-gather (32 lines/instr). Fix: A staged through LDS with
//  * coalesced swizzled SOURCE: lane l of wave w reads 16B of row (w*8+(l>>3))
//    at k-slot 16B*((l&7)^((l>>3)&7)) — XOR is a bijection on the row's eight
//    16B slots, so 8 lanes cover one full 128B line => 8 lines/instr.
//  * linear LDS dest (global_load_lds requirement, m104/m173).
//  * swizzled fragment READ: byte = row*128 + (inner ^ ((row&7)<<4)) — lanes
//    0-15 spread over 8 bank-quads = 2-way conflict = free (m136).
// Round trip: read(row,i) -> stored inner i^((row&7)<<4) -> holds
// x[row][i ^ s ^ s] = x[row][i]. Verified algebraically.
// grid = 128 mt x 4 ksp = 512 (2 blocks/CU); 512 thr = 8 waves (2wm x 4wn),
// wave tile 32x64; LDS 2x32KB (B) + 2x8KB (A) = 80 KB.
// ---------------------------------------------------------------------------
__global__ __launch_bounds__(512, 2) void gemm_split_kernel(
    const float* __restrict__ x, const short* __restrict__ wsp,
    float* __restrict__ part, int Btok)
{
    __shared__ short Blds[2][BT_ELEMS];   // 2 x 32 KB
    __shared__ float Alds[2][BM * BK];    // 2 x 8 KB

    const int bid  = blockIdx.x;
    const int xcd  = bid & 7;
    const int ksp  = xcd & 3;
    const int mt   = (bid >> 3) * 2 + (xcd >> 2);   // 0..127, bijective
    const int m0   = mt * BM;
    const int kbase = ksp * KPER;
    const int t    = threadIdx.x;
    const int wid  = t >> 6, lane = t & 63;
    const int wm   = wid >> 2, wn = wid & 3;
    const int lr   = lane & 15, lg = lane >> 4;

    const short* wt0 = wsp + (size_t)(ksp * NSTEP) * BT_ELEMS;

    // A staging source (pre-swizzled, coalesced): one instr per wave per step
    const int arow  = wid * 8 + (lane >> 3);                  // 0..63
    const int akoff = 4 * ((lane & 7) ^ ((lane >> 3) & 7));   // float offset in 32-k row
    const float* asrc0 = x + (size_t)(m0 + arow) * DDIM + kbase + akoff;
    const int adst_off = wid * 1024 + lane * 16;              // linear LDS bytes

#define STAGE_B(stp, buf) do {                                                             \
        const short* gt_ = wt0 + (size_t)(stp) * BT_ELEMS;                                 \
        _Pragma("unroll")                                                                  \
        for (int i_ = 0; i_ < 4; i_++) {                                                   \
            const int off_ = wid * 4096 + i_ * 1024;                                       \
            __builtin_amdgcn_global_load_lds(                                              \
                (const __attribute__((address_space(1))) u32*)((const char*)gt_ + off_ + lane * 16), \
                (__attribute__((address_space(3))) u32*)((char*)&Blds[buf][0] + off_),     \
                16, 0, 0);                                                                 \
        } } while (0)

#define STAGE_A(stp, buf) do {                                                             \
        __builtin_amdgcn_global_load_lds(                                                  \
            (const __attribute__((address_space(1))) u32*)(asrc0 + (size_t)(stp) * BK),    \
            (__attribute__((address_space(3))) u32*)((char*)&Alds[buf][0] + adst_off),     \
            16, 0, 0);                                                                     \
    } while (0)

    f32x4 acc[2][4];
    #pragma unroll
    for (int i = 0; i < 2; i++)
        #pragma unroll
        for (int j = 0; j < 4; j++) acc[i][j] = (f32x4){0.f, 0.f, 0.f, 0.f};

    // ---- prologue ----
    STAGE_B(0, 0);
    STAGE_A(0, 0);

    for (int st = 0; st < NSTEP; st++) {
        const int cur = st & 1;
        // waits vmcnt(0)+lgkmcnt(0): A(st)/B(st) DMA resident; prior reads done
        __syncthreads();

        // ---- issue next-step staging (lands during this step's compute) ----
        if (st + 1 < NSTEP) {
            STAGE_B(st + 1, cur ^ 1);
            STAGE_A(st + 1, cur ^ 1);
        }

        // ---- A fragments from LDS (swizzled read) + hi/lo convert ----
        const char* ab = (const char*)&Alds[cur][0];
        bf16x8 ah[2], al[2];
        #pragma unroll
        for (int fm = 0; fm < 2; fm++) {
            const int row = wm * 32 + fm * 16 + lr;
            const int rb  = row * 128;
            const int sw  = (lr & 7) << 4;          // row&7 == lr&7 here
            float fr[8];
            *(float4*)&fr[0] = *(const float4*)(ab + rb + ((lg * 32) ^ sw));
            *(float4*)&fr[4] = *(const float4*)(ab + rb + ((lg * 32 + 16) ^ sw));
            union { bf16x8 v; short s[8]; } H, L;
            #pragma unroll
            for (int j = 0; j < 8; j++)
                split_elem(fr[j], H.s[j], L.s[j]);
            ah[fm] = H.v;
            al[fm] = L.v;
        }

        // ---- B fragments (lane-linear) + MFMA, pass-major ----
        bf16x8 bhv[4], blv[4];
        #pragma unroll
        for (int fn = 0; fn < 4; fn++) {
            bhv[fn] = *(const bf16x8*)&Blds[cur][((size_t)(0 * 16 + wn * 4 + fn) * 64 + lane) * 8];
            blv[fn] = *(const bf16x8*)&Blds[cur][((size_t)(1 * 16 + wn * 4 + fn) * 64 + lane) * 8];
        }
        #pragma unroll
        for (int fn = 0; fn < 4; fn++)
            #pragma unroll
            for (int fm = 0; fm < 2; fm++)
                acc[fm][fn] = __builtin_amdgcn_mfma_f32_16x16x32_bf16(ah[fm], bhv[fn], acc[fm][fn], 0, 0, 0);
        #pragma unroll
        for (int fn = 0; fn < 4; fn++)
            #pragma unroll
            for (int fm = 0; fm < 2; fm++)
                acc[fm][fn] = __builtin_amdgcn_mfma_f32_16x16x32_bf16(ah[fm], blv[fn], acc[fm][fn], 0, 0, 0);
        #pragma unroll
        for (int fn = 0; fn < 4; fn++)
            #pragma unroll
            for (int fm = 0; fm < 2; fm++)
                acc[fm][fn] = __builtin_amdgcn_mfma_f32_16x16x32_bf16(al[fm], bhv[fn], acc[fm][fn], 0, 0, 0);
    }
#undef STAGE_B
#undef STAGE_A

    // ---- epilogue: fp32 partials (C/D map: col=lane&15, row=(lane>>4)*4+reg) ----
    float* pp = part + (size_t)ksp * (size_t)Btok * NEXP;
    #pragma unroll
    for (int fm = 0; fm < 2; fm++) {
        const int row0 = m0 + wm * 32 + fm * 16 + lg * 4;
        #pragma unroll
        for (int fn = 0; fn < 4; fn++) {
            const int col = wn * 64 + fn * 16 + lr;
            #pragma unroll
            for (int rr = 0; rr < 4; rr++)
                pp[(size_t)(row0 + rr) * NEXP + col] = acc[fm][fn][rr];
        }
    }
}

// ---------------------------------------------------------------------------
// Kernel 2: reduce split-K partials + sigmoid + full gating, one wave per row.
// (unchanged — proven)
// ---------------------------------------------------------------------------
__global__ __launch_bounds__(256) void gate_kernel(
    const float* __restrict__ part, const float* __restrict__ bias,
    float* __restrict__ out_w, float* __restrict__ out_i, int B)
{
    const int lane = threadIdx.x & 63;
    const int wid  = threadIdx.x >> 6;
    const int row  = blockIdx.x * 4 + wid;
    if (row >= B) return;

    const size_t plane = (size_t)B * NEXP;
    const float* pr = part + (size_t)row * NEXP + lane * 4;
    float4 v0 = *(const float4*)(pr);
    float4 v1 = *(const float4*)(pr + plane);
    float4 v2 = *(const float4*)(pr + 2 * plane);
    float4 v3 = *(const float4*)(pr + 3 * plane);
    float sc[4] = { v0.x + v1.x + v2.x + v3.x,
                    v0.y + v1.y + v2.y + v3.y,
                    v0.z + v1.z + v2.z + v3.z,
                    v0.w + v1.w + v2.w + v3.w };
    float4 bv = *(const float4*)(bias + lane * 4);
    const float bb[4] = { bv.x, bv.y, bv.z, bv.w };

    float so[4], sb[4];
    #pragma unroll
    for (int j = 0; j < 4; j++) {
        so[j] = 1.0f / (1.0f + expf(-sc[j]));
        sb[j] = so[j] + bb[j];
    }

    float m1 = sb[0], m2 = -INFINITY;
    #pragma unroll
    for (int j = 1; j < 4; j++) {
        if (sb[j] > m1)      { m2 = m1; m1 = sb[j]; }
        else if (sb[j] > m2) { m2 = sb[j]; }
    }
    #pragma unroll
    for (int m = 1; m <= 4; m <<= 1) {
        float o1 = __shfl_xor(m1, m);
        float o2 = __shfl_xor(m2, m);
        float hi = fmaxf(m1, o1);
        float lo = fminf(m1, o1);
        m1 = hi;
        m2 = fmaxf(lo, fmaxf(m2, o2));
    }
    float gscore = m1 + m2;
    int g = lane >> 3;

    float gs[NGRP];
    #pragma unroll
    for (int gg = 0; gg < NGRP; gg++) gs[gg] = __shfl(gscore, gg * 8);
    int rank = 0;
    #pragma unroll
    for (int gg = 0; gg < NGRP; gg++) {
        if (gg == g) continue;
        if (gs[gg] > gs[g] || (gs[gg] == gs[g] && gg < g)) rank++;
    }
    const bool selg = (rank < TOPKG);
    float mv[4];
    #pragma unroll
    for (int j = 0; j < 4; j++) mv[j] = selg ? sb[j] : -INFINITY;

    float wsel[TOPK];
    int   isel[TOPK];
    float wsum = 0.f;
    #pragma unroll
    for (int it = 0; it < TOPK; it++) {
        float v = mv[0]; int jj = 0;
        #pragma unroll
        for (int j = 1; j < 4; j++)
            if (mv[j] > v) { v = mv[j]; jj = j; }
        int gi = (lane << 2) | jj;
        #pragma unroll
        for (int m = 1; m < 64; m <<= 1) {
            float ov = __shfl_xor(v, m);
            int   oi = __shfl_xor(gi, m);
            if (ov > v || (ov == v && oi < gi)) { v = ov; gi = oi; }
        }
        int slot = gi & 3, src = gi >> 2;
        float cand = (slot == 0) ? so[0] : (slot == 1) ? so[1] : (slot == 2) ? so[2] : so[3];
        float sval = __shfl(cand, src);
        wsel[it] = sval; isel[it] = gi; wsum += sval;
        if (lane == src) mv[slot] = -INFINITY;
    }

    if (lane == 0) {
        float scl = ROUTE_SCALE / wsum;
        #pragma unroll
        for (int it = 0; it < TOPK; it++) {
            out_w[(size_t)row * TOPK + it] = wsel[it] * scl;
            out_i[(size_t)row * TOPK + it] = (float)isel[it];
        }
    }
}

extern "C" void kernel_launch(void* const* d_in, const int* in_sizes, int n_in,
                              void* d_out, int out_size, void* d_ws, size_t ws_size,
                              hipStream_t stream)
{
    const float* x    = (const float*)d_in[0];
    const float* w    = (const float*)d_in[1];
    const float* bias = (const float*)d_in[2];
    const int B = in_sizes[0] / DDIM;           // 8192

    // ws layout: [ part: 4 * B * 256 f32 = 32 MB ][ wsp: 224 tiles * 32 KB = 7.34 MB ]
    float* part = (float*)d_ws;
    short* wsp  = (short*)((char*)d_ws + (size_t)KSPLIT * B * NEXP * sizeof(float));

    float* out_w = (float*)d_out;
    float* out_i = out_w + (size_t)B * TOPK;

    hipLaunchKernelGGL(wsplit_kernel, dim3(NKTILE), dim3(256), 0, stream, w, wsp);
    hipLaunchKernelGGL(gemm_split_kernel, dim3((B / BM) * KSPLIT), dim3(512), 0, stream,
                       x, wsp, part, B);
    hipLaunchKernelGGL(gate_kernel, dim3((B + 3) / 4), dim3(256), 0, stream,
                       part, bias, out_w, out_i, B);
}